// Round 7
// baseline (236.054 us; speedup 1.0000x reference)
//
#include <hip/hip_runtime.h>

typedef float fx4 __attribute__((ext_vector_type(4)));   // native vec types for nontemporal builtins
typedef float fx2 __attribute__((ext_vector_type(2)));

__device__ __forceinline__ void nt_store4(float4* p, float4 v) {
    fx4 vv = {v.x, v.y, v.z, v.w};
    __builtin_nontemporal_store(vv, (fx4*)p);
}
__device__ __forceinline__ float4 nt_load4(const float4* p) {
    fx4 vv = __builtin_nontemporal_load((const fx4*)p);
    float4 r; r.x = vv.x; r.y = vv.y; r.z = vv.z; r.w = vv.w;
    return r;
}
__device__ __forceinline__ float2 nt_load2(const float2* p) {
    fx2 vv = __builtin_nontemporal_load((const fx2*)p);
    float2 r; r.x = vv.x; r.y = vv.y;
    return r;
}

// Quad permute via DPP (VALU, no LDS/DS, no lgkmcnt): out[lane] = in[quad[lane&3]]
template<int CTRL>
__device__ __forceinline__ float qperm(float v) {
    return __int_as_float(__builtin_amdgcn_update_dpp(
        0, __float_as_int(v), CTRL, 0xF, 0xF, true));
}
template<int CTRL>
__device__ __forceinline__ float4 qperm4(float4 v) {
    float4 r;
    r.x = qperm<CTRL>(v.x);
    r.y = qperm<CTRL>(v.y);
    r.z = qperm<CTRL>(v.z);
    r.w = qperm<CTRL>(v.w);
    return r;
}

// quad_perm ctrl byte: [1:0]=src for lane0, [3:2]=lane1, [5:4]=lane2, [7:6]=lane3
#define ROT1 0xC9   // [1,2,0,3]: lane r<3 reads lane (r+1)%3
#define ROT2 0xD2   // [2,0,1,3]: lane r<3 reads lane (r+2)%3
#define BC0  0x00   // broadcast lane 0
#define BC1  0x55   // broadcast lane 1
#define BC2  0xAA   // broadcast lane 2
#define BC3  0xFF   // broadcast lane 3

// 4 lanes per pose: lane j -> pose p=j>>2, row r=j&3.
// VMEM per pose: 3 wave-instructions total (was 5):
//   1x cooperative xi load  (lane r loads x2[min(r,2)]; 32B/quad requested, 24B unique)
//   1x dwordx4 pose load    (perfectly coalesced)
//   1x dwordx4 store        (perfectly coalesced, nontemporal)
// xi scalars distributed within the quad by 6 DPP broadcasts (VALU only ~13% busy).
// All loads nontemporal: pure streaming data, bypass L1 allocation (confirmed +15% in R6).
__global__ __launch_bounds__(256) void se3_compose_kernel(
    const float* __restrict__ xi,
    const float4* __restrict__ poses4,   // flat float4 view, length 4*n
    float4* __restrict__ out4,           // flat float4 view, length 4*n
    int n4)                              // = 4*n
{
    int i = blockIdx.x * blockDim.x + threadIdx.x;
    if (i >= n4) return;

    int p = i >> 2;   // pose index
    int r = i & 3;    // my row / quad role

    // ---- cooperative xi load: ONE instruction for the whole quad ----
    int rc = (r < 2) ? r : 2;                       // lane3 duplicates lane2's line (coalesces)
    const float2* x2 = (const float2*)(xi + 6ll * p);
    float2 f = nt_load2(x2 + rc);

    // ---- my pose row: perfectly coalesced float4 ----
    float4 pr = nt_load4(&poses4[i]);

    // ---- distribute xi within the quad (6 DPP broadcasts) ----
    float t0 = qperm<BC0>(f.x), t1 = qperm<BC0>(f.y);   // lane0 held (t0,t1)
    float t2 = qperm<BC1>(f.x), w0 = qperm<BC1>(f.y);   // lane1 held (t2,w0)
    float w1 = qperm<BC2>(f.x), w2 = qperm<BC2>(f.y);   // lane2 held (w1,w2)

    // ---- A = sin(t)/t, B = (1-cos(t))/t^2, series in x = t^2 ----
    float x = w0 * w0 + w1 * w1 + w2 * w2;
    float A, B;
    if (__builtin_expect(x < 2.25f, 1)) {
        // |err| < ~1.5e-6 for theta < 1.5; series limit == reference small-angle branch
        A = 1.0f + x * (-1.0f / 6.0f  + x * (1.0f / 120.0f + x * (-1.0f / 5040.0f  + x * (1.0f / 362880.0f))));
        B = 0.5f + x * (-1.0f / 24.0f + x * (1.0f / 720.0f + x * (-1.0f / 40320.0f + x * (1.0f / 3628800.0f))));
    } else {
        // exact fallback (never taken for this distribution; keeps kernel general)
        float th = sqrtf(x);
        A = sinf(th) / th;
        B = (1.0f - cosf(th)) / x;
    }

    // ---- per-row values (cyclic Rodrigues) ----
    float wr = (r == 0) ? w0 : (r == 1) ? w1 : w2;
    float tr = (r == 0) ? t0 : (r == 1) ? t1 : (r == 2) ? t2 : 0.0f;

    float wa = qperm<ROT1>(wr);   // w[(r+1)%3]
    float wb = qperm<ROT2>(wr);   // w[(r+2)%3]

    float4 Pa = qperm4<ROT1>(pr); // pose row (r+1)%3
    float4 Pb = qperm4<ROT2>(pr); // pose row (r+2)%3
    float4 P3 = qperm4<BC3>(pr);  // pose row 3

    float diag = 1.0f - B * (wa * wa + wb * wb);
    float off1 = B * wr * wa - A * wb;
    float off2 = B * wr * wb + A * wa;
    if (r == 3) { diag = 1.0f; off1 = 0.0f; off2 = 0.0f; }  // T row3 = [0,0,0,1]

    float4 o;
    o.x = diag * pr.x + off1 * Pa.x + off2 * Pb.x + tr * P3.x;
    o.y = diag * pr.y + off1 * Pa.y + off2 * Pb.y + tr * P3.y;
    o.z = diag * pr.z + off1 * Pa.z + off2 * Pb.z + tr * P3.z;
    o.w = diag * pr.w + off1 * Pa.w + off2 * Pb.w + tr * P3.w;

    nt_store4(&out4[i], o);   // coalesced: wave writes 1KB contiguous
}

extern "C" void kernel_launch(void* const* d_in, const int* in_sizes, int n_in,
                              void* d_out, int out_size, void* d_ws, size_t ws_size,
                              hipStream_t stream) {
    const float*  xi     = (const float*)d_in[0];
    const float4* poses4 = (const float4*)d_in[1];
    float4*       out4   = (float4*)d_out;

    int n  = in_sizes[0] / 6;  // N = 2,000,000
    int n4 = 4 * n;

    const int block = 256;
    const int grid  = (n4 + block - 1) / block;
    se3_compose_kernel<<<grid, block, 0, stream>>>(xi, poses4, out4, n4);
}